// Round 9
// baseline (450.823 us; speedup 1.0000x reference)
//
#include <hip/hip_runtime.h>
#include <cstdint>
#include <cstddef>

#define E_ 8
#define D_ 1024
#define F_ 4096
#define T_ 16384
#define C_ 2048   // tokens per expert

typedef __attribute__((ext_vector_type(8))) short short8;
typedef __attribute__((ext_vector_type(4))) float f32x4;

// fp32 -> bf16 round-to-nearest-even
__device__ __forceinline__ unsigned short f2b(float f) {
  union { float f; uint32_t u; } v; v.f = f;
  uint32_t u = v.u;
  return (unsigned short)((u + 0x7FFFu + ((u >> 16) & 1u)) >> 16);
}

// tanh-approx gelu (jax.nn.gelu default approximate=True)
__device__ __forceinline__ float gelu_t(float x) {
  float u = 0.7978845608028654f * (x + 0.044715f * x * x * x);
  float e = __expf(2.0f * u);
  return 0.5f * x * (2.0f - 2.0f / (e + 1.0f));  // 0.5x(1+tanh(u))
}

__device__ __forceinline__ void gload_lds16(const void* g, void* l) {
  __builtin_amdgcn_global_load_lds(
      (__attribute__((address_space(1))) void*)g,
      (__attribute__((address_space(3))) void*)l, 16, 0, 0);
}

#define MEMFENCE() asm volatile("" ::: "memory")
#define BAR() do { MEMFENCE(); __builtin_amdgcn_s_barrier(); MEMFENCE(); } while (0)

// ---------------- pre-pass: fp32 -> bf16 elementwise ----------------
__global__ void cvt_bf16_kernel(const float* __restrict__ in,
                                unsigned short* __restrict__ out, int n) {
  int idx = blockIdx.x * blockDim.x + threadIdx.x;
  int stride = gridDim.x * blockDim.x;
  for (int i = idx * 8; i < n; i += stride * 8) {
    float4 a = *(const float4*)(in + i);
    float4 b = *(const float4*)(in + i + 4);
    union { unsigned short s[8]; int4 v; } r;
    r.s[0] = f2b(a.x); r.s[1] = f2b(a.y); r.s[2] = f2b(a.z); r.s[3] = f2b(a.w);
    r.s[4] = f2b(b.x); r.s[5] = f2b(b.y); r.s[6] = f2b(b.z); r.s[7] = f2b(b.w);
    *(int4*)(out + i) = r.v;
  }
}

// ---------------- pre-pass: per-expert transpose + convert ----------------
// in: [E][R][Cc] fp32  ->  out: [E][Cc][R] bf16
__global__ void transpose_cvt(const float* __restrict__ in,
                              unsigned short* __restrict__ out, int R, int Cc) {
  __shared__ float tile_s[32][33];
  const int e = blockIdx.y;
  const int ctiles = Cc >> 5;
  const int rt = blockIdx.x / ctiles, ct = blockIdx.x % ctiles;
  const int r0 = rt * 32, c0 = ct * 32;
  const float* ine = in + (size_t)e * R * Cc;
  unsigned short* oute = out + (size_t)e * R * Cc;
  const int tx = threadIdx.x & 31, ty = threadIdx.x >> 5;  // ty in 0..7
#pragma unroll
  for (int q = 0; q < 4; ++q)
    tile_s[ty + q * 8][tx] = ine[(size_t)(r0 + ty + q * 8) * Cc + c0 + tx];
  __syncthreads();
#pragma unroll
  for (int q = 0; q < 4; ++q) {
    float v = tile_s[tx][ty + q * 8];
    oute[(size_t)(c0 + ty + q * 8) * R + r0 + tx] = f2b(v);
  }
}

// ==== 256x128 batched bf16 GEMM, BK=32, ring-3, 2 blocks/CU ==============
// A: [E][Mt][Kt] bf16 row-major; B: [E][Nt][Kt] bf16 (row = output column).
// 512 thr = 8 waves (2M x 4N); per-wave 128x32 output; acc[2][4][2].
// LDS: 3 ring buffers x (A[256][32] + B[128][32]) = 72 KB -> 2 blocks/CU.
// LDS line layout: 128B line holds rows {2j,2j+1} x 4 k-slots, 8 16B slots
// XOR-permuted by (line&7): slot(r,s) = ((s<<1)|(r&1)) ^ ((r>>1)&7).
// Staging: chunk c -> line=c>>3,pos=c&7,o=pos^(line&7): row=(line<<1)|(o&1),
// gk=o>>1; LDS dest linear c*16B (both-sides swizzle, conflict-free reads).
// Loop: reads(t); stage(t+2); MFMA; vmcnt(3 counted); lgkm(0); one barrier.
// EPI==1: bf16 h with bias+gelu (LDS bounce). EPI==2: fp32 + bias (bounce).
template <int Mt, int Nt, int Kt, int EPI>
__global__ __launch_bounds__(512, 4)
void gemmO(const unsigned short* __restrict__ A,
           const unsigned short* __restrict__ B,
           const float* __restrict__ bias, void* __restrict__ Cout) {
  constexpr int NT = Kt / 32;
  constexpr int MB = Mt / 256, NB = Nt / 128;
  static_assert(NT >= 3, "");

  // bijective XCD swizzle (nwg % 8 == 0 for all our grids)
  const int nwg = E_ * MB * NB;
  const int bid = blockIdx.x;
  const int swzb = (bid & 7) * (nwg >> 3) + (bid >> 3);
  const int e = swzb / (MB * NB);
  const int rem = swzb % (MB * NB);
  const int mblk = rem / NB, nblk = rem % NB;

  const unsigned short* Ae = A + ((size_t)e * Mt + mblk * 256) * Kt;
  const unsigned short* Be = B + ((size_t)e * Nt + nblk * 128) * Kt;

  __shared__ unsigned short lds[36864];  // 72 KB

  const int tid = threadIdx.x;
  const int lane = tid & 63, wave = tid >> 6;
  const int wm = wave >> 2, wn = wave & 3;  // 2M x 4N
  const int ls = lane >> 4, lr = lane & 15;

  // staging chunk decode
  auto decode = [](int c, int& row, int& gk) {
    int line = c >> 3, pos = c & 7, o = pos ^ (line & 7);
    row = (line << 1) | (o & 1);
    gk = o >> 1;
  };
  const int cA0 = tid, cA1 = tid + 512, cB = tid;
  int rA0, kA0, rA1, kA1, rB, kB;
  decode(cA0, rA0, kA0); decode(cA1, rA1, kA1); decode(cB, rB, kB);

  auto stage = [&](int t) {
    unsigned short* bufA = lds + (t % 3) * 12288;
    unsigned short* bufB = bufA + 8192;
    const unsigned short* As = Ae + t * 32;
    const unsigned short* Bs = Be + t * 32;
    gload_lds16(As + (size_t)rA0 * Kt + kA0 * 8, bufA + cA0 * 8);
    gload_lds16(As + (size_t)rA1 * Kt + kA1 * 8, bufA + cA1 * 8);
    gload_lds16(Bs + (size_t)rB * Kt + kB * 8, bufB + cB * 8);
  };

  // bias first (oldest vmem; retired by prologue vmcnt)
  const float* be = bias + (size_t)e * Nt + nblk * 128;
  float bv[2];
#pragma unroll
  for (int n = 0; n < 2; ++n) bv[n] = be[wn * 32 + n * 16 + lr];

  // hoisted LDS read offsets (in shorts): line=(r>>1)*64, slot 8 shorts
  auto roff = [&](int r) {
    return (r >> 1) * 64 + (((((ls << 1) | (r & 1)) ^ ((r >> 1) & 7))) << 3);
  };
  int offA[2][4], offB[2];
#pragma unroll
  for (int mh = 0; mh < 2; ++mh)
#pragma unroll
    for (int m = 0; m < 4; ++m) offA[mh][m] = roff(wm * 128 + mh * 64 + m * 16 + lr);
#pragma unroll
  for (int n = 0; n < 2; ++n) offB[n] = roff(wn * 32 + n * 16 + lr);

  f32x4 acc[2][4][2] = {};

  stage(0); stage(1);
  asm volatile("s_waitcnt vmcnt(3)" ::: "memory");  // bias + stage(0) landed
  BAR();

  for (int t = 0; t < NT; ++t) {
    const unsigned short* bufA = lds + (t % 3) * 12288;
    const unsigned short* bufB = bufA + 8192;
    short8 fb[2], fa0[4], fa1[4];
#pragma unroll
    for (int n = 0; n < 2; ++n) fb[n] = *(const short8*)(bufB + offB[n]);
#pragma unroll
    for (int m = 0; m < 4; ++m) fa0[m] = *(const short8*)(bufA + offA[0][m]);
    if (t + 2 < NT) stage(t + 2);
#pragma unroll
    for (int m = 0; m < 4; ++m) fa1[m] = *(const short8*)(bufA + offA[1][m]);

    __builtin_amdgcn_s_setprio(1);
#pragma unroll
    for (int m = 0; m < 4; ++m)
#pragma unroll
      for (int n = 0; n < 2; ++n)
        acc[0][m][n] =
            __builtin_amdgcn_mfma_f32_16x16x32_bf16(fa0[m], fb[n], acc[0][m][n], 0, 0, 0);
#pragma unroll
    for (int m = 0; m < 4; ++m)
#pragma unroll
      for (int n = 0; n < 2; ++n)
        acc[1][m][n] =
            __builtin_amdgcn_mfma_f32_16x16x32_bf16(fa1[m], fb[n], acc[1][m][n], 0, 0, 0);
    __builtin_amdgcn_s_setprio(0);

    // retire stage(t+1) (counted; never 0 mid-loop); reads retired; rendezvous
    if (t + 2 < NT) asm volatile("s_waitcnt vmcnt(3)" ::: "memory");
    else            asm volatile("s_waitcnt vmcnt(0)" ::: "memory");
    asm volatile("s_waitcnt lgkmcnt(0)" ::: "memory");
    BAR();
  }

  if constexpr (EPI == 1) {
    // bounce: lds as [256][128] ushort, 16B-chunk XOR (ch ^= row&7)
    unsigned short* lb = lds;
#pragma unroll
    for (int mh = 0; mh < 2; ++mh)
#pragma unroll
      for (int m = 0; m < 4; ++m)
#pragma unroll
        for (int n = 0; n < 2; ++n)
#pragma unroll
          for (int i = 0; i < 4; ++i) {
            int row = wm * 128 + mh * 64 + m * 16 + ls * 4 + i;
            int col = wn * 32 + n * 16 + lr;
            lb[row * 128 + (((col >> 3) ^ (row & 7)) << 3) + (col & 7)] =
                f2b(gelu_t(acc[mh][m][n][i] + bv[n]));
          }
    BAR();
    unsigned short* H = (unsigned short*)Cout;
#pragma unroll
    for (int q = 0; q < 8; ++q) {
      int idx = q * 512 + tid;
      int row = idx >> 4, ch = idx & 15;
      int sc = ch ^ (row & 7);
      unsigned short* dst =
          H + ((size_t)e * Mt + mblk * 256 + row) * Nt + nblk * 128 + ch * 8;
      *(int4*)dst = *(const int4*)(lb + row * 128 + sc * 8);
    }
  } else {
    // fp32 bounce: two half-tiles through padded LDS [128][132] f32
    float* fl = (float*)lds;  // 128*132*4 = 67584 B <= 73728
    float* O = (float*)Cout;
#pragma unroll
    for (int h = 0; h < 2; ++h) {
      if (wm == h) {
#pragma unroll
        for (int mh = 0; mh < 2; ++mh)
#pragma unroll
          for (int m = 0; m < 4; ++m)
#pragma unroll
            for (int n = 0; n < 2; ++n)
#pragma unroll
              for (int i = 0; i < 4; ++i) {
                int rl = mh * 64 + m * 16 + ls * 4 + i;
                int col = wn * 32 + n * 16 + lr;
                fl[rl * 132 + col] = acc[mh][m][n][i] + bv[n];
              }
      }
      BAR();
#pragma unroll
      for (int q = 0; q < 8; ++q) {
        int v = q * 512 + tid;
        int row = v >> 5, c4 = v & 31;
        float* dst = O + ((size_t)e * Mt + mblk * 256 + h * 128 + row) * Nt +
                     nblk * 128 + c4 * 4;
        *(float4*)dst = *(const float4*)(fl + row * 132 + c4 * 4);
      }
      if (h == 0) BAR();
    }
  }
}

extern "C" void kernel_launch(void* const* d_in, const int* in_sizes, int n_in,
                              void* d_out, int out_size, void* d_ws, size_t ws_size,
                              hipStream_t stream) {
  const float* x = (const float*)d_in[0];
  const float* w1 = (const float*)d_in[1];
  const float* b1 = (const float*)d_in[2];
  const float* w2 = (const float*)d_in[3];
  const float* b2 = (const float*)d_in[4];
  float* out = (float*)d_out;

  unsigned short* ws = (unsigned short*)d_ws;
  unsigned short* xb = ws;                               // [T][D] bf16
  unsigned short* w1t = xb + (size_t)T_ * D_;            // [E][F][D] bf16
  unsigned short* w2t = w1t + (size_t)E_ * F_ * D_;      // [E][D][F] bf16
  unsigned short* h = w2t + (size_t)E_ * D_ * F_;        // [T][F] bf16

  cvt_bf16_kernel<<<2048, 256, 0, stream>>>(x, xb, T_ * D_);
  transpose_cvt<<<dim3((D_ / 32) * (F_ / 32), E_), 256, 0, stream>>>(w1, w1t, D_, F_);
  transpose_cvt<<<dim3((F_ / 32) * (D_ / 32), E_), 256, 0, stream>>>(w2, w2t, F_, D_);

  gemmO<C_, F_, D_, 1>
      <<<E_ * (C_ / 256) * (F_ / 128), 512, 0, stream>>>(xb, w1t, b1, h);
  gemmO<C_, D_, F_, 2>
      <<<E_ * (C_ / 256) * (D_ / 128), 512, 0, stream>>>(h, w2t, b2, out);
}